// Round 1
// baseline (807.289 us; speedup 1.0000x reference)
//
#include <hip/hip_runtime.h>
#include <hip/hip_bf16.h>

#define T_SEQ 2048
#define HID   1024
#define NH    16
#define HD    64
#define NB    2

typedef __bf16 bf16_t;
typedef bf16_t bf16x8 __attribute__((ext_vector_type(8)));
typedef bf16_t bf16x4 __attribute__((ext_vector_type(4)));
typedef float  f32x4  __attribute__((ext_vector_type(4)));

static __device__ __forceinline__ f32x4 mfma16(bf16x8 a, bf16x8 b, f32x4 c) {
    return __builtin_amdgcn_mfma_f32_16x16x32_bf16(a, b, c, 0, 0, 0);
}

// C[M x 1024] = A[M x 1024] @ W^T, W is [1024 x 1024] row-major (torch Linear).
// AMODE 0: A is f32 (convert in-register). AMODE 1: A is bf16.
// OMODE 0: bf16 out [M][1024]. OMODE 1: bf16 out transposed to [B][H][D][T] (for V).
// OMODE 2: f32 out [M][1024].
template<int AMODE, int OMODE>
__global__ __launch_bounds__(256) void gemm_xw(const void* __restrict__ Av,
                                               const float* __restrict__ W,
                                               void* __restrict__ outv, int M) {
    const int wid  = blockIdx.x * 4 + (threadIdx.x >> 6);
    const int lane = threadIdx.x & 63;
    const int NT   = HID / 64;          // 16 column tiles
    const int mt = wid / NT, nt = wid % NT;
    const int row0 = mt * 64, col0 = nt * 64;
    const int lr = lane & 15;
    const int kd = (lane >> 4) * 8;

    f32x4 acc[4][4] = {};

    for (int k = 0; k < HID; k += 32) {
        bf16x8 af[4], bq[4];
#pragma unroll
        for (int i = 0; i < 4; ++i) {
            if (AMODE == 0) {
                const float* ap = (const float*)Av + (size_t)(row0 + i*16 + lr) * HID + k + kd;
                float4 a0 = *(const float4*)ap;
                float4 a1 = *(const float4*)(ap + 4);
                af[i][0]=(bf16_t)a0.x; af[i][1]=(bf16_t)a0.y; af[i][2]=(bf16_t)a0.z; af[i][3]=(bf16_t)a0.w;
                af[i][4]=(bf16_t)a1.x; af[i][5]=(bf16_t)a1.y; af[i][6]=(bf16_t)a1.z; af[i][7]=(bf16_t)a1.w;
            } else {
                af[i] = *(const bf16x8*)((const bf16_t*)Av + (size_t)(row0 + i*16 + lr) * HID + k + kd);
            }
        }
#pragma unroll
        for (int j = 0; j < 4; ++j) {
            const float* wp = W + (size_t)(col0 + j*16 + lr) * HID + k + kd;
            float4 b0 = *(const float4*)wp;
            float4 b1 = *(const float4*)(wp + 4);
            bq[j][0]=(bf16_t)b0.x; bq[j][1]=(bf16_t)b0.y; bq[j][2]=(bf16_t)b0.z; bq[j][3]=(bf16_t)b0.w;
            bq[j][4]=(bf16_t)b1.x; bq[j][5]=(bf16_t)b1.y; bq[j][6]=(bf16_t)b1.z; bq[j][7]=(bf16_t)b1.w;
        }
#pragma unroll
        for (int i = 0; i < 4; ++i)
#pragma unroll
            for (int j = 0; j < 4; ++j)
                acc[i][j] = mfma16(af[i], bq[j], acc[i][j]);
    }

    const int rb = (lane >> 4) * 4;
#pragma unroll
    for (int i = 0; i < 4; ++i) {
#pragma unroll
        for (int j = 0; j < 4; ++j) {
            const int col = col0 + j*16 + lr;
            if (OMODE == 0) {
                bf16_t* ob = (bf16_t*)outv;
#pragma unroll
                for (int r = 0; r < 4; ++r)
                    ob[(size_t)(row0 + i*16 + rb + r) * HID + col] = (bf16_t)acc[i][j][r];
            } else if (OMODE == 1) {
                const int row = row0 + i*16 + rb;      // 4 consecutive rows (= t)
                const int bb = row >> 11, t = row & (T_SEQ - 1);
                const int hh = col >> 6,  d = col & 63;
                bf16x4 pk;
#pragma unroll
                for (int r = 0; r < 4; ++r) pk[r] = (bf16_t)acc[i][j][r];
                *(bf16x4*)((bf16_t*)outv + ((size_t)((bb*NH + hh)*HD + d))*T_SEQ + t) = pk;
            } else {
                float* of = (float*)outv;
#pragma unroll
                for (int r = 0; r < 4; ++r)
                    of[(size_t)(row0 + i*16 + rb + r) * HID + col] = acc[i][j][r];
            }
        }
    }
}

// Fused rel-shift attention.
// Q,K: [B,T,H,D] bf16. VT: [B,H,D,T] bf16. RK: [T,H,D] bf16. AO: [B,T,H*D] bf16.
// One block = 4 independent waves; wave w owns query rows [t0+16w, t0+16w+16).
// Exact rel_shift semantics (incl. unmasked upper-triangle leak):
//   s<=t   : (q[t]+bv)  . relk[T-1-(t-s)]
//   s==t+1 : 0
//   s>=t+2 : (q[t+1]+bv). relk[s-t-2]
__global__ __launch_bounds__(256) void attn_kernel(
    const bf16_t* __restrict__ Q, const bf16_t* __restrict__ K,
    const bf16_t* __restrict__ VT, const bf16_t* __restrict__ RK,
    const float* __restrict__ bias_u, const float* __restrict__ bias_v,
    bf16_t* __restrict__ AO)
{
    const int w = threadIdx.x >> 6, lane = threadIdx.x & 63;
    const int t0 = blockIdx.x * 64;
    const int h = blockIdx.y, b = blockIdx.z;
    const int lr = lane & 15, lkg = lane >> 4;
    const int kd = lkg * 8;

    __shared__ float  pp1[4][16][132];   // stride 132: bank-spread rows
    __shared__ float  pp2[4][16][132];
    __shared__ bf16_t pl [4][16][72];    // stride 72 (144B): 16B-aligned, bank-spread

    const int tb = t0 + w * 16;

    // Per-wave A-fragments: qu = q+bias_u (rows t), qv = q+bias_v (rows t),
    // qv2 = q+bias_v (rows t+1, clamped; only used where s>=t+2 exists).
    bf16x8 aqu[2], aqv[2], aqv2[2];
    {
        const int t  = tb + lr;
        const int t2 = (t + 1 < T_SEQ) ? t + 1 : T_SEQ - 1;
        const bf16_t* qp  = Q + ((size_t)(b*T_SEQ + t )*NH + h)*HD;
        const bf16_t* qp2 = Q + ((size_t)(b*T_SEQ + t2)*NH + h)*HD;
        const float* bu = bias_u + h*HD;
        const float* bv = bias_v + h*HD;
#pragma unroll
        for (int f = 0; f < 2; ++f) {
            const int k0 = f*32 + kd;
            bf16x8 q1 = *(const bf16x8*)(qp  + k0);
            bf16x8 q2 = *(const bf16x8*)(qp2 + k0);
#pragma unroll
            for (int j = 0; j < 8; ++j) {
                const float fu = bu[k0+j], fv = bv[k0+j];
                aqu [f][j] = (bf16_t)((float)q1[j] + fu);
                aqv [f][j] = (bf16_t)((float)q1[j] + fv);
                aqv2[f][j] = (bf16_t)((float)q2[j] + fv);
            }
        }
    }

    float m_run[4], l_run[4];
    f32x4 oacc[4];
    f32x4 zf = {0.f, 0.f, 0.f, 0.f};
#pragma unroll
    for (int r = 0; r < 4; ++r) { m_run[r] = -1e30f; l_run[r] = 0.0f; }
#pragma unroll
    for (int nf = 0; nf < 4; ++nf) oacc[nf] = zf;

    const bf16_t* Kb = K  + (size_t)(b*T_SEQ)*HID + h*HD;
    const bf16_t* Vb = VT + (size_t)((b*NH + h)*HD)*T_SEQ;
    const bf16_t* Rb = RK + h*HD;

    for (int s0 = 0; s0 < T_SEQ; s0 += 64) {
        // ---- content scores (q+bu).k : 4 col-frags x K=64
        f32x4 sc[4];
#pragma unroll
        for (int j = 0; j < 4; ++j) {
            const bf16_t* kp = Kb + (size_t)(s0 + j*16 + lr) * HID;
            bf16x8 b0 = *(const bf16x8*)(kp + kd);
            bf16x8 b1 = *(const bf16x8*)(kp + 32 + kd);
            sc[j] = mfma16(aqu[1], b1, mfma16(aqu[0], b0, zf));
        }

        // ---- positional parallelogram GEMMs into per-wave LDS
        const int base1 = s0 - t0 + T_SEQ - 64;       // c1 window start
        if (s0 <= t0 + 63) {                          // branch s<=t reachable
#pragma unroll
            for (int jf = 0; jf < 8; ++jf) {
                const int c1 = base1 + jf*16 + lr;
                bf16x8 b0 = {}, b1 = {};
                if ((unsigned)c1 < (unsigned)T_SEQ) {
                    const bf16_t* rp = Rb + (size_t)c1 * HID;
                    b0 = *(const bf16x8*)(rp + kd);
                    b1 = *(const bf16x8*)(rp + 32 + kd);
                }
                f32x4 c = mfma16(aqv[1], b1, mfma16(aqv[0], b0, zf));
#pragma unroll
                for (int r = 0; r < 4; ++r) pp1[w][lkg*4 + r][jf*16 + lr] = c[r];
            }
        }
        if (s0 >= t0 - 61) {                          // branch s>=t+2 reachable
            const int base2 = base1 - (T_SEQ + 1);
#pragma unroll
            for (int jf = 0; jf < 8; ++jf) {
                const int c2 = base2 + jf*16 + lr;
                bf16x8 b0 = {}, b1 = {};
                if ((unsigned)c2 < (unsigned)T_SEQ) {
                    const bf16_t* rp = Rb + (size_t)c2 * HID;
                    b0 = *(const bf16x8*)(rp + kd);
                    b1 = *(const bf16x8*)(rp + 32 + kd);
                }
                f32x4 c = mfma16(aqv2[1], b1, mfma16(aqv2[0], b0, zf));
#pragma unroll
                for (int r = 0; r < 4; ++r) pp2[w][lkg*4 + r][jf*16 + lr] = c[r];
            }
        }

        // ---- diagonal gather + online softmax (per reg-row; row = 16-lane group)
#pragma unroll
        for (int r = 0; r < 4; ++r) {
            const int rr = lkg*4 + r;
            const int t = t0 + w*16 + rr;
            float vls[4];
            float mx = -1e30f;
#pragma unroll
            for (int j = 0; j < 4; ++j) {
                const int s = s0 + j*16 + lr;
                const int dt = s - t;
                const int jwin = (s - s0) - (t - t0) + 63;   // 0..126
                float pos;
                if (dt <= 0)      pos = pp1[w][rr][jwin];
                else if (dt == 1) pos = 0.0f;
                else              pos = pp2[w][rr][jwin];
                const float val = (sc[j][r] + pos) * 0.125f;
                vls[j] = val;
                mx = fmaxf(mx, val);
            }
#pragma unroll
            for (int off = 1; off < 16; off <<= 1)
                mx = fmaxf(mx, __shfl_xor(mx, off, 64));
            const float mnew = fmaxf(m_run[r], mx);
            const float fac = __expf(m_run[r] - mnew);
            float sum = 0.f;
#pragma unroll
            for (int j = 0; j < 4; ++j) {
                const float p = __expf(vls[j] - mnew);
                sum += p;
                pl[w][rr][j*16 + lr] = (bf16_t)p;
            }
#pragma unroll
            for (int off = 1; off < 16; off <<= 1)
                sum += __shfl_xor(sum, off, 64);
            l_run[r] = l_run[r] * fac + sum;
            m_run[r] = mnew;
#pragma unroll
            for (int nf = 0; nf < 4; ++nf) oacc[nf][r] *= fac;
        }

        // ---- PV: O += P @ V  (P from LDS as A-frags; V^T rows contiguous)
        bf16x8 pa0 = *(const bf16x8*)(&pl[w][lr][kd]);
        bf16x8 pa1 = *(const bf16x8*)(&pl[w][lr][32 + kd]);
#pragma unroll
        for (int nf = 0; nf < 4; ++nf) {
            const bf16_t* vp = Vb + (size_t)(nf*16 + lr) * T_SEQ + s0;
            bf16x8 b0 = *(const bf16x8*)(vp + kd);
            bf16x8 b1 = *(const bf16x8*)(vp + 32 + kd);
            oacc[nf] = mfma16(pa1, b1, mfma16(pa0, b0, oacc[nf]));
        }
    }

    // ---- epilogue: normalize, store [B,T,H*D] bf16
#pragma unroll
    for (int r = 0; r < 4; ++r) {
        const int rr = lkg*4 + r;
        const int t = t0 + w*16 + rr;
        const float inv = 1.0f / l_run[r];
#pragma unroll
        for (int nf = 0; nf < 4; ++nf)
            AO[(size_t)(b*T_SEQ + t)*HID + h*HD + nf*16 + lr] = (bf16_t)(oacc[nf][r] * inv);
    }
}

extern "C" void kernel_launch(void* const* d_in, const int* in_sizes, int n_in,
                              void* d_out, int out_size, void* d_ws, size_t ws_size,
                              hipStream_t stream) {
    const float* x    = (const float*)d_in[0];
    const float* pos  = (const float*)d_in[1];
    const float* Wq   = (const float*)d_in[2];
    const float* Wk   = (const float*)d_in[3];
    const float* Wv   = (const float*)d_in[4];
    const float* Wo   = (const float*)d_in[5];
    const float* Wrel = (const float*)d_in[6];
    const float* bu   = (const float*)d_in[7];
    const float* bv   = (const float*)d_in[8];

    // workspace (bf16 elems): q 4M | k 4M | vT 4M | relk 2M | attn_out 4M = 36 MB
    bf16_t* ws  = (bf16_t*)d_ws;
    const size_t M1 = 1024u * 1024u;
    bf16_t* qb  = ws;
    bf16_t* kb  = ws + 4*M1;
    bf16_t* vtb = ws + 8*M1;
    bf16_t* rkb = ws + 12*M1;
    bf16_t* ab  = ws + 14*M1;

    // projections: y = x @ W^T  (M=4096 -> 256 blocks of 4 waves; M=2048 -> 128)
    gemm_xw<0,0><<<256, 256, 0, stream>>>(x,   Wq,   qb,  4096);
    gemm_xw<0,0><<<256, 256, 0, stream>>>(x,   Wk,   kb,  4096);
    gemm_xw<0,1><<<256, 256, 0, stream>>>(x,   Wv,   vtb, 4096);
    gemm_xw<0,0><<<128, 256, 0, stream>>>(pos, Wrel, rkb, 2048);

    attn_kernel<<<dim3(T_SEQ/64, NH, NB), 256, 0, stream>>>(qb, kb, vtb, rkb, bu, bv, ab);

    gemm_xw<1,2><<<256, 256, 0, stream>>>(ab, Wo, d_out, 4096);
}

// Round 2
// 748.483 us; speedup vs baseline: 1.0786x; 1.0786x over previous
//
#include <hip/hip_runtime.h>
#include <hip/hip_bf16.h>

#define T_SEQ 2048
#define HID   1024
#define NH    16
#define HD    64
#define NB    2

typedef __bf16 bf16_t;
typedef bf16_t bf16x8 __attribute__((ext_vector_type(8)));
typedef bf16_t bf16x4 __attribute__((ext_vector_type(4)));
typedef float  f32x4  __attribute__((ext_vector_type(4)));

static __device__ __forceinline__ f32x4 mfma16(bf16x8 a, bf16x8 b, f32x4 c) {
    return __builtin_amdgcn_mfma_f32_16x16x32_bf16(a, b, c, 0, 0, 0);
}

// C[M x 1024] = A[M x 1024] @ W^T, W is [1024 x 1024] row-major (torch Linear).
// AMODE 0: A is f32 (convert in-register). AMODE 1: A is bf16.
// OMODE 0: bf16 out [M][1024]. OMODE 1: bf16 out transposed to [B][H][D][T] (for V).
// OMODE 2: f32 out [M][1024].
template<int AMODE, int OMODE>
__global__ __launch_bounds__(256) void gemm_xw(const void* __restrict__ Av,
                                               const float* __restrict__ W,
                                               void* __restrict__ outv, int M) {
    const int wid  = blockIdx.x * 4 + (threadIdx.x >> 6);
    const int lane = threadIdx.x & 63;
    const int NT   = HID / 64;          // 16 column tiles
    const int mt = wid / NT, nt = wid % NT;
    const int row0 = mt * 64, col0 = nt * 64;
    const int lr = lane & 15;
    const int kd = (lane >> 4) * 8;

    f32x4 acc[4][4] = {};

    for (int k = 0; k < HID; k += 32) {
        bf16x8 af[4], bq[4];
#pragma unroll
        for (int i = 0; i < 4; ++i) {
            if (AMODE == 0) {
                const float* ap = (const float*)Av + (size_t)(row0 + i*16 + lr) * HID + k + kd;
                float4 a0 = *(const float4*)ap;
                float4 a1 = *(const float4*)(ap + 4);
                af[i][0]=(bf16_t)a0.x; af[i][1]=(bf16_t)a0.y; af[i][2]=(bf16_t)a0.z; af[i][3]=(bf16_t)a0.w;
                af[i][4]=(bf16_t)a1.x; af[i][5]=(bf16_t)a1.y; af[i][6]=(bf16_t)a1.z; af[i][7]=(bf16_t)a1.w;
            } else {
                af[i] = *(const bf16x8*)((const bf16_t*)Av + (size_t)(row0 + i*16 + lr) * HID + k + kd);
            }
        }
#pragma unroll
        for (int j = 0; j < 4; ++j) {
            const float* wp = W + (size_t)(col0 + j*16 + lr) * HID + k + kd;
            float4 b0 = *(const float4*)wp;
            float4 b1 = *(const float4*)(wp + 4);
            bq[j][0]=(bf16_t)b0.x; bq[j][1]=(bf16_t)b0.y; bq[j][2]=(bf16_t)b0.z; bq[j][3]=(bf16_t)b0.w;
            bq[j][4]=(bf16_t)b1.x; bq[j][5]=(bf16_t)b1.y; bq[j][6]=(bf16_t)b1.z; bq[j][7]=(bf16_t)b1.w;
        }
#pragma unroll
        for (int i = 0; i < 4; ++i)
#pragma unroll
            for (int j = 0; j < 4; ++j)
                acc[i][j] = mfma16(af[i], bq[j], acc[i][j]);
    }

    const int rb = (lane >> 4) * 4;
#pragma unroll
    for (int i = 0; i < 4; ++i) {
#pragma unroll
        for (int j = 0; j < 4; ++j) {
            const int col = col0 + j*16 + lr;
            if (OMODE == 0) {
                bf16_t* ob = (bf16_t*)outv;
#pragma unroll
                for (int r = 0; r < 4; ++r)
                    ob[(size_t)(row0 + i*16 + rb + r) * HID + col] = (bf16_t)acc[i][j][r];
            } else if (OMODE == 1) {
                const int row = row0 + i*16 + rb;      // 4 consecutive rows (= t)
                const int bb = row >> 11, t = row & (T_SEQ - 1);
                const int hh = col >> 6,  d = col & 63;
                bf16x4 pk;
#pragma unroll
                for (int r = 0; r < 4; ++r) pk[r] = (bf16_t)acc[i][j][r];
                *(bf16x4*)((bf16_t*)outv + ((size_t)((bb*NH + hh)*HD + d))*T_SEQ + t) = pk;
            } else {
                float* of = (float*)outv;
#pragma unroll
                for (int r = 0; r < 4; ++r)
                    of[(size_t)(row0 + i*16 + rb + r) * HID + col] = acc[i][j][r];
            }
        }
    }
}

// Fused rel-shift attention.
// Q,K: [B,T,H,D] bf16. VT: [B,H,D,T] bf16. RK: [T,H,D] bf16. AO: [B,T,H*D] bf16.
// One block = 4 independent waves; wave w owns query rows [t0+16w, t0+16w+16).
// Exact rel_shift semantics (incl. unmasked upper-triangle leak):
//   s<=t   : (q[t]+bv)  . relk[T-1-(t-s)]
//   s==t+1 : 0
//   s>=t+2 : (q[t+1]+bv). relk[s-t-2]
// Per-wave 80-wide pos window (5 frags), single pp buffer reused by the two
// branches (in-wave DS ops are in-order -> two-pass gather is safe).
// 0.125 softmax scale is folded (exactly) into the bf16 q-fragments.
__global__ __launch_bounds__(256) void attn_kernel(
    const bf16_t* __restrict__ Q, const bf16_t* __restrict__ K,
    const bf16_t* __restrict__ VT, const bf16_t* __restrict__ RK,
    const float* __restrict__ bias_u, const float* __restrict__ bias_v,
    bf16_t* __restrict__ AO)
{
    const int w = threadIdx.x >> 6, lane = threadIdx.x & 63;
    const int t0 = blockIdx.x * 64;
    const int h = blockIdx.y, b = blockIdx.z;
    const int lr = lane & 15, lkg = lane >> 4;
    const int kd = lkg * 8;

    __shared__ float  pp[4][16][84];     // per-wave 16x80 window, stride 84
    __shared__ bf16_t pl[4][16][72];     // P staging, stride 72 (144B)

    const int tb = t0 + w * 16;

    // A-fragments (x0.125 folded, exact pow2): qu=(q[t]+bu)/8, qv=(q[t]+bv)/8,
    // qv2=(q[t+1]+bv)/8 (clamped row; only gathered where s>=t+2 exists).
    bf16x8 aqu[2], aqv[2], aqv2[2];
    {
        const int t  = tb + lr;
        const int t2 = (t + 1 < T_SEQ) ? t + 1 : T_SEQ - 1;
        const bf16_t* qp  = Q + ((size_t)(b*T_SEQ + t )*NH + h)*HD;
        const bf16_t* qp2 = Q + ((size_t)(b*T_SEQ + t2)*NH + h)*HD;
        const float* bu = bias_u + h*HD;
        const float* bv = bias_v + h*HD;
#pragma unroll
        for (int f = 0; f < 2; ++f) {
            const int k0 = f*32 + kd;
            bf16x8 q1 = *(const bf16x8*)(qp  + k0);
            bf16x8 q2 = *(const bf16x8*)(qp2 + k0);
#pragma unroll
            for (int j = 0; j < 8; ++j) {
                const float fu = bu[k0+j], fv = bv[k0+j];
                aqu [f][j] = (bf16_t)(((float)q1[j] + fu) * 0.125f);
                aqv [f][j] = (bf16_t)(((float)q1[j] + fv) * 0.125f);
                aqv2[f][j] = (bf16_t)(((float)q2[j] + fv) * 0.125f);
            }
        }
    }

    float m_run[4], l_run[4];
    f32x4 oacc[4];
    f32x4 zf = {0.f, 0.f, 0.f, 0.f};
#pragma unroll
    for (int r = 0; r < 4; ++r) { m_run[r] = -1e30f; l_run[r] = 0.0f; }
#pragma unroll
    for (int nf = 0; nf < 4; ++nf) oacc[nf] = zf;

    const bf16_t* Kb = K  + (size_t)(b*T_SEQ)*HID + h*HD;
    const bf16_t* Vb = VT + (size_t)((b*NH + h)*HD)*T_SEQ;
    const bf16_t* Rb = RK + h*HD;

    for (int s0 = 0; s0 < T_SEQ; s0 += 64) {
        // ---- content scores (q+bu).k (already x0.125): 4 col-frags x K=64
        f32x4 sc[4];
#pragma unroll
        for (int j = 0; j < 4; ++j) {
            const bf16_t* kp = Kb + (size_t)(s0 + j*16 + lr) * HID;
            bf16x8 b0 = *(const bf16x8*)(kp + kd);
            bf16x8 b1 = *(const bf16x8*)(kp + 32 + kd);
            sc[j] = mfma16(aqu[1], b1, mfma16(aqu[0], b0, zf));
        }

        // dt = s - t = (s0 + j*16 + lr_col) - (tb + rr); jwin = j*16+lr_col - rr + 15
        // ---- branch 1 (s<=t): window c1 = (s0-tb+T-16) + jwin, jwin in [0,78]
        if (s0 <= tb + 15) {
            const int base1 = s0 - tb + T_SEQ - 16;
#pragma unroll
            for (int jf = 0; jf < 5; ++jf) {
                const int c1 = base1 + jf*16 + lr;
                bf16x8 b0 = {}, b1 = {};
                if ((unsigned)c1 < (unsigned)T_SEQ) {
                    const bf16_t* rp = Rb + (size_t)c1 * HID;
                    b0 = *(const bf16x8*)(rp + kd);
                    b1 = *(const bf16x8*)(rp + 32 + kd);
                }
                f32x4 c = mfma16(aqv[1], b1, mfma16(aqv[0], b0, zf));
#pragma unroll
                for (int r = 0; r < 4; ++r) pp[w][lkg*4 + r][jf*16 + lr] = c[r];
            }
#pragma unroll
            for (int r = 0; r < 4; ++r) {
                const int rr = lkg*4 + r;
#pragma unroll
                for (int j = 0; j < 4; ++j) {
                    const float v = pp[w][rr][j*16 + lr - rr + 15];
                    const int dt = (s0 + j*16 + lr) - (tb + rr);
                    sc[j][r] += (dt <= 0) ? v : 0.0f;
                }
            }
        }
        // ---- branch 2 (s>=t+2, query row t+1): c2 = (s0-tb-17) + jwin
        if (s0 >= tb - 61) {
            const int base2 = s0 - tb - 17;
#pragma unroll
            for (int jf = 0; jf < 5; ++jf) {
                const int c2 = base2 + jf*16 + lr;
                bf16x8 b0 = {}, b1 = {};
                if ((unsigned)c2 < (unsigned)T_SEQ) {
                    const bf16_t* rp = Rb + (size_t)c2 * HID;
                    b0 = *(const bf16x8*)(rp + kd);
                    b1 = *(const bf16x8*)(rp + 32 + kd);
                }
                f32x4 c = mfma16(aqv2[1], b1, mfma16(aqv2[0], b0, zf));
#pragma unroll
                for (int r = 0; r < 4; ++r) pp[w][lkg*4 + r][jf*16 + lr] = c[r];
            }
#pragma unroll
            for (int r = 0; r < 4; ++r) {
                const int rr = lkg*4 + r;
#pragma unroll
                for (int j = 0; j < 4; ++j) {
                    const float v = pp[w][rr][j*16 + lr - rr + 15];
                    const int dt = (s0 + j*16 + lr) - (tb + rr);
                    sc[j][r] += (dt >= 2) ? v : 0.0f;
                }
            }
        }

        // ---- online softmax (per reg-row; row = one 16-lane group's reg r)
#pragma unroll
        for (int r = 0; r < 4; ++r) {
            const int rr = lkg*4 + r;
            float mx = fmaxf(fmaxf(sc[0][r], sc[1][r]), fmaxf(sc[2][r], sc[3][r]));
#pragma unroll
            for (int off = 1; off < 16; off <<= 1)
                mx = fmaxf(mx, __shfl_xor(mx, off, 64));
            const float mnew = fmaxf(m_run[r], mx);
            const float fac = __expf(m_run[r] - mnew);
            float sum = 0.f;
#pragma unroll
            for (int j = 0; j < 4; ++j) {
                const float p = __expf(sc[j][r] - mnew);
                sum += p;
                pl[w][rr][j*16 + lr] = (bf16_t)p;
            }
#pragma unroll
            for (int off = 1; off < 16; off <<= 1)
                sum += __shfl_xor(sum, off, 64);
            l_run[r] = l_run[r] * fac + sum;
            m_run[r] = mnew;
#pragma unroll
            for (int nf = 0; nf < 4; ++nf) oacc[nf][r] *= fac;
        }

        // ---- PV: O += P @ V  (P from LDS as A-frags; V^T rows contiguous)
        bf16x8 pa0 = *(const bf16x8*)(&pl[w][lr][kd]);
        bf16x8 pa1 = *(const bf16x8*)(&pl[w][lr][32 + kd]);
#pragma unroll
        for (int nf = 0; nf < 4; ++nf) {
            const bf16_t* vp = Vb + (size_t)(nf*16 + lr) * T_SEQ + s0;
            bf16x8 b0 = *(const bf16x8*)(vp + kd);
            bf16x8 b1 = *(const bf16x8*)(vp + 32 + kd);
            oacc[nf] = mfma16(pa1, b1, mfma16(pa0, b0, oacc[nf]));
        }
    }

    // ---- epilogue: normalize, store [B,T,H*D] bf16
#pragma unroll
    for (int r = 0; r < 4; ++r) {
        const int rr = lkg*4 + r;
        const int t = t0 + w*16 + rr;
        const float inv = 1.0f / l_run[r];
#pragma unroll
        for (int nf = 0; nf < 4; ++nf)
            AO[(size_t)(b*T_SEQ + t)*HID + h*HD + nf*16 + lr] = (bf16_t)(oacc[nf][r] * inv);
    }
}

extern "C" void kernel_launch(void* const* d_in, const int* in_sizes, int n_in,
                              void* d_out, int out_size, void* d_ws, size_t ws_size,
                              hipStream_t stream) {
    const float* x    = (const float*)d_in[0];
    const float* pos  = (const float*)d_in[1];
    const float* Wq   = (const float*)d_in[2];
    const float* Wk   = (const float*)d_in[3];
    const float* Wv   = (const float*)d_in[4];
    const float* Wo   = (const float*)d_in[5];
    const float* Wrel = (const float*)d_in[6];
    const float* bu   = (const float*)d_in[7];
    const float* bv   = (const float*)d_in[8];

    // workspace (bf16 elems): q 4M | k 4M | vT 4M | relk 2M | attn_out 4M = 36 MB
    bf16_t* ws  = (bf16_t*)d_ws;
    const size_t M1 = 1024u * 1024u;
    bf16_t* qb  = ws;
    bf16_t* kb  = ws + 4*M1;
    bf16_t* vtb = ws + 8*M1;
    bf16_t* rkb = ws + 12*M1;
    bf16_t* ab  = ws + 14*M1;

    // projections: y = x @ W^T  (M=4096 -> 256 blocks of 4 waves; M=2048 -> 128)
    gemm_xw<0,0><<<256, 256, 0, stream>>>(x,   Wq,   qb,  4096);
    gemm_xw<0,0><<<256, 256, 0, stream>>>(x,   Wk,   kb,  4096);
    gemm_xw<0,1><<<256, 256, 0, stream>>>(x,   Wv,   vtb, 4096);
    gemm_xw<0,0><<<128, 256, 0, stream>>>(pos, Wrel, rkb, 2048);

    attn_kernel<<<dim3(T_SEQ/64, NH, NB), 256, 0, stream>>>(qb, kb, vtb, rkb, bu, bv, ab);

    gemm_xw<1,2><<<256, 256, 0, stream>>>(ab, Wo, d_out, 4096);
}

// Round 3
// 666.226 us; speedup vs baseline: 1.2117x; 1.1235x over previous
//
#include <hip/hip_runtime.h>
#include <hip/hip_bf16.h>

#define T_SEQ 2048
#define HID   1024
#define NH    16
#define HD    64
#define NB    2

typedef __bf16 bf16_t;
typedef bf16_t bf16x8 __attribute__((ext_vector_type(8)));
typedef bf16_t bf16x4 __attribute__((ext_vector_type(4)));
typedef float  f32x4  __attribute__((ext_vector_type(4)));

static __device__ __forceinline__ f32x4 mfma16(bf16x8 a, bf16x8 b, f32x4 c) {
    return __builtin_amdgcn_mfma_f32_16x16x32_bf16(a, b, c, 0, 0, 0);
}

// C[M x 1024] = A[M x 1024] @ W^T, W is [1024 x 1024] row-major (torch Linear).
// AMODE 0: A is f32 (convert in-register). AMODE 1: A is bf16.
// OMODE 0: bf16 out [M][1024]. OMODE 1: bf16 out transposed to [B][H][D][T] (for V).
// OMODE 2: f32 out [M][1024].
template<int AMODE, int OMODE>
__global__ __launch_bounds__(256) void gemm_xw(const void* __restrict__ Av,
                                               const float* __restrict__ W,
                                               void* __restrict__ outv, int M) {
    const int wid  = blockIdx.x * 4 + (threadIdx.x >> 6);
    const int lane = threadIdx.x & 63;
    const int NT   = HID / 64;          // 16 column tiles
    const int mt = wid / NT, nt = wid % NT;
    const int row0 = mt * 64, col0 = nt * 64;
    const int lr = lane & 15;
    const int kd = (lane >> 4) * 8;

    f32x4 acc[4][4] = {};

    for (int k = 0; k < HID; k += 32) {
        bf16x8 af[4], bq[4];
#pragma unroll
        for (int i = 0; i < 4; ++i) {
            if (AMODE == 0) {
                const float* ap = (const float*)Av + (size_t)(row0 + i*16 + lr) * HID + k + kd;
                float4 a0 = *(const float4*)ap;
                float4 a1 = *(const float4*)(ap + 4);
                af[i][0]=(bf16_t)a0.x; af[i][1]=(bf16_t)a0.y; af[i][2]=(bf16_t)a0.z; af[i][3]=(bf16_t)a0.w;
                af[i][4]=(bf16_t)a1.x; af[i][5]=(bf16_t)a1.y; af[i][6]=(bf16_t)a1.z; af[i][7]=(bf16_t)a1.w;
            } else {
                af[i] = *(const bf16x8*)((const bf16_t*)Av + (size_t)(row0 + i*16 + lr) * HID + k + kd);
            }
        }
#pragma unroll
        for (int j = 0; j < 4; ++j) {
            const float* wp = W + (size_t)(col0 + j*16 + lr) * HID + k + kd;
            float4 b0 = *(const float4*)wp;
            float4 b1 = *(const float4*)(wp + 4);
            bq[j][0]=(bf16_t)b0.x; bq[j][1]=(bf16_t)b0.y; bq[j][2]=(bf16_t)b0.z; bq[j][3]=(bf16_t)b0.w;
            bq[j][4]=(bf16_t)b1.x; bq[j][5]=(bf16_t)b1.y; bq[j][6]=(bf16_t)b1.z; bq[j][7]=(bf16_t)b1.w;
        }
#pragma unroll
        for (int i = 0; i < 4; ++i)
#pragma unroll
            for (int j = 0; j < 4; ++j)
                acc[i][j] = mfma16(af[i], bq[j], acc[i][j]);
    }

    const int rb = (lane >> 4) * 4;
#pragma unroll
    for (int i = 0; i < 4; ++i) {
#pragma unroll
        for (int j = 0; j < 4; ++j) {
            const int col = col0 + j*16 + lr;
            if (OMODE == 0) {
                bf16_t* ob = (bf16_t*)outv;
#pragma unroll
                for (int r = 0; r < 4; ++r)
                    ob[(size_t)(row0 + i*16 + rb + r) * HID + col] = (bf16_t)acc[i][j][r];
            } else if (OMODE == 1) {
                const int row = row0 + i*16 + rb;      // 4 consecutive rows (= t)
                const int bb = row >> 11, t = row & (T_SEQ - 1);
                const int hh = col >> 6,  d = col & 63;
                bf16x4 pk;
#pragma unroll
                for (int r = 0; r < 4; ++r) pk[r] = (bf16_t)acc[i][j][r];
                *(bf16x4*)((bf16_t*)outv + ((size_t)((bb*NH + hh)*HD + d))*T_SEQ + t) = pk;
            } else {
                float* of = (float*)outv;
#pragma unroll
                for (int r = 0; r < 4; ++r)
                    of[(size_t)(row0 + i*16 + rb + r) * HID + col] = acc[i][j][r];
            }
        }
    }
}

// Fused rel-shift attention, SWAPPED orientation.
// Q,K: [B,T,H,D] bf16. VT: [B,H,D,T] bf16. RK: [T,H,D] bf16. AO: [B,T,H*D] bf16.
// One block = 4 independent waves; wave w owns query rows [tb, tb+16), tb=t0+16w.
// All QK-type MFMAs computed as mfma(K_frag, Q_frag) so lane layout is
// D[s-row = 4*(lane>>4)+reg][q-col = lane&15]: each lane holds 16 s-values of
// ONE q-row (q = tb + (lane&15)) -> softmax row-reduce is in-lane + 2 shfl_xor.
// PV output keeps D[q-row=4lkg+r][d-col=lr]; fac/l are bpermute'd across.
// Exact rel_shift semantics (incl. unmasked upper-triangle leak):
//   s<=t   : (q[t]+bv)  . relk[T-1-(t-s)]
//   s==t+1 : 0
//   s>=t+2 : (q[t+1]+bv). relk[s-t-2]
// 0.125 softmax scale folded (exactly) into the bf16 q-fragments.
__global__ __launch_bounds__(256) void attn_kernel(
    const bf16_t* __restrict__ Q, const bf16_t* __restrict__ K,
    const bf16_t* __restrict__ VT, const bf16_t* __restrict__ RK,
    const float* __restrict__ bias_u, const float* __restrict__ bias_v,
    bf16_t* __restrict__ AO)
{
    const int w = threadIdx.x >> 6, lane = threadIdx.x & 63;
    const int t0 = blockIdx.x * 64;
    const int h = blockIdx.y, b = blockIdx.z;
    const int lr = lane & 15, lkg = lane >> 4;
    const int kd = lkg * 8;

    __shared__ float  pp[4][16][84];     // [wave][q(=lr)][window col], f32x4 writes
    __shared__ bf16_t pl[4][16][72];     // [wave][q(=lr)][s offset], stride 72

    const int tb = t0 + w * 16;

    // Fragments (B-operand role; same lane mapping as A): qu=(q[t]+bu)/8,
    // qv=(q[t]+bv)/8, qv2=(q[t+1]+bv)/8, t = tb+lr (clamped row for qv2).
    bf16x8 aqu[2], aqv[2], aqv2[2];
    {
        const int t  = tb + lr;
        const int t2 = (t + 1 < T_SEQ) ? t + 1 : T_SEQ - 1;
        const bf16_t* qp  = Q + ((size_t)(b*T_SEQ + t )*NH + h)*HD;
        const bf16_t* qp2 = Q + ((size_t)(b*T_SEQ + t2)*NH + h)*HD;
        const float* bu = bias_u + h*HD;
        const float* bv = bias_v + h*HD;
#pragma unroll
        for (int f = 0; f < 2; ++f) {
            const int k0 = f*32 + kd;
            bf16x8 q1 = *(const bf16x8*)(qp  + k0);
            bf16x8 q2 = *(const bf16x8*)(qp2 + k0);
#pragma unroll
            for (int j = 0; j < 8; ++j) {
                const float fu = bu[k0+j], fv = bv[k0+j];
                aqu [f][j] = (bf16_t)(((float)q1[j] + fu) * 0.125f);
                aqv [f][j] = (bf16_t)(((float)q1[j] + fv) * 0.125f);
                aqv2[f][j] = (bf16_t)(((float)q2[j] + fv) * 0.125f);
            }
        }
    }

    float m_run = -1e30f, l_run = 0.0f;   // per-lane stats for q = tb + lr
    f32x4 oacc[4];                        // [d-frag]: rows q=4lkg+r, col d=16nf+lr
    f32x4 zf = {0.f, 0.f, 0.f, 0.f};
#pragma unroll
    for (int nf = 0; nf < 4; ++nf) oacc[nf] = zf;

    const bf16_t* Kb = K  + (size_t)(b*T_SEQ)*HID + h*HD;
    const bf16_t* Vb = VT + (size_t)((b*NH + h)*HD)*T_SEQ;
    const bf16_t* Rb = RK + h*HD;
    const int d15 = 15 - lr;

    for (int s0 = 0; s0 < T_SEQ; s0 += 64) {
        // ---- content scores swapped: sc[j][r] = S[s=s0+16j+4lkg+r][q=tb+lr]
        f32x4 sc[4];
#pragma unroll
        for (int j = 0; j < 4; ++j) {
            const bf16_t* kp = Kb + (size_t)(s0 + j*16 + lr) * HID;
            bf16x8 a0 = *(const bf16x8*)(kp + kd);
            bf16x8 a1 = *(const bf16x8*)(kp + 32 + kd);
            sc[j] = mfma16(a1, aqu[1], mfma16(a0, aqu[0], zf));
        }

        // jwin = (s-s0) - lr + 15 = sof + d15, sof = 16j+4lkg+r in [0,63]
        // ---- branch 1 (s<=t): c1 = (s0-tb+T-16) + jwin
        if (s0 <= tb + 15) {
            const int base1 = s0 - tb + T_SEQ - 16;
#pragma unroll
            for (int jf = 0; jf < 5; ++jf) {
                const int c1 = base1 + jf*16 + lr;
                bf16x8 a0 = {}, a1 = {};
                if ((unsigned)c1 < (unsigned)T_SEQ) {
                    const bf16_t* rp = Rb + (size_t)c1 * HID;
                    a0 = *(const bf16x8*)(rp + kd);
                    a1 = *(const bf16x8*)(rp + 32 + kd);
                }
                f32x4 c = mfma16(a1, aqv[1], mfma16(a0, aqv[0], zf));
                *(f32x4*)&pp[w][lr][jf*16 + 4*lkg] = c;   // D[wcol=4lkg+r'][q=lr]
            }
#pragma unroll
            for (int j = 0; j < 4; ++j)
#pragma unroll
                for (int r = 0; r < 4; ++r) {
                    const int sof = 16*j + 4*lkg + r;
                    const int dt  = (s0 + sof) - (tb + lr);
                    const float v = pp[w][lr][sof + d15];
                    sc[j][r] += (dt <= 0) ? v : 0.0f;
                }
        }
        // ---- branch 2 (s>=t+2, query row t+1): c2 = (s0-tb-17) + jwin
        if (s0 >= tb - 61) {
            const int base2 = s0 - tb - 17;
#pragma unroll
            for (int jf = 0; jf < 5; ++jf) {
                const int c2 = base2 + jf*16 + lr;
                bf16x8 a0 = {}, a1 = {};
                if ((unsigned)c2 < (unsigned)T_SEQ) {
                    const bf16_t* rp = Rb + (size_t)c2 * HID;
                    a0 = *(const bf16x8*)(rp + kd);
                    a1 = *(const bf16x8*)(rp + 32 + kd);
                }
                f32x4 c = mfma16(a1, aqv2[1], mfma16(a0, aqv2[0], zf));
                *(f32x4*)&pp[w][lr][jf*16 + 4*lkg] = c;
            }
#pragma unroll
            for (int j = 0; j < 4; ++j)
#pragma unroll
                for (int r = 0; r < 4; ++r) {
                    const int sof = 16*j + 4*lkg + r;
                    const int dt  = (s0 + sof) - (tb + lr);
                    const float v = pp[w][lr][sof + d15];
                    sc[j][r] += (dt >= 2) ? v : 0.0f;
                }
        }

        // ---- online softmax: whole row is in-lane (16 vals) + 2 shfls
        float mx = fmaxf(fmaxf(fmaxf(sc[0][0], sc[0][1]), fmaxf(sc[0][2], sc[0][3])),
                         fmaxf(fmaxf(sc[1][0], sc[1][1]), fmaxf(sc[1][2], sc[1][3])));
        mx = fmaxf(mx, fmaxf(fmaxf(fmaxf(sc[2][0], sc[2][1]), fmaxf(sc[2][2], sc[2][3])),
                             fmaxf(fmaxf(sc[3][0], sc[3][1]), fmaxf(sc[3][2], sc[3][3]))));
        mx = fmaxf(mx, __shfl_xor(mx, 16, 64));
        mx = fmaxf(mx, __shfl_xor(mx, 32, 64));
        const float mnew = fmaxf(m_run, mx);
        const float fac = __expf(m_run - mnew);
        float sum = 0.0f;
#pragma unroll
        for (int j = 0; j < 4; ++j) {
            bf16x4 pk;
#pragma unroll
            for (int r = 0; r < 4; ++r) {
                const float p = __expf(sc[j][r] - mnew);
                sum += p;
                pk[r] = (bf16_t)p;
            }
            *(bf16x4*)&pl[w][lr][16*j + 4*lkg] = pk;     // P[q=lr][s=16j+4lkg+r]
        }
        sum += __shfl_xor(sum, 16, 64);
        sum += __shfl_xor(sum, 32, 64);
        l_run = l_run * fac + sum;
        m_run = mnew;

        // rescale O: rows are q=4lkg+r -> broadcast fac from lane (4lkg+r)
#pragma unroll
        for (int r = 0; r < 4; ++r) {
            const float facq = __shfl(fac, 4*lkg + r, 64);
#pragma unroll
            for (int nf = 0; nf < 4; ++nf) oacc[nf][r] *= facq;
        }

        // ---- PV: O += P @ V  (P A-frags from LDS; V^T rows contiguous)
        bf16x8 pa0 = *(const bf16x8*)(&pl[w][lr][kd]);
        bf16x8 pa1 = *(const bf16x8*)(&pl[w][lr][32 + kd]);
#pragma unroll
        for (int nf = 0; nf < 4; ++nf) {
            const bf16_t* vp = Vb + (size_t)(nf*16 + lr) * T_SEQ + s0;
            bf16x8 b0 = *(const bf16x8*)(vp + kd);
            bf16x8 b1 = *(const bf16x8*)(vp + 32 + kd);
            oacc[nf] = mfma16(pa1, b1, mfma16(pa0, b0, oacc[nf]));
        }
    }

    // ---- epilogue: normalize (broadcast 1/l to PV rows), store [B,T,H*D] bf16
    const float linv = 1.0f / l_run;
#pragma unroll
    for (int r = 0; r < 4; ++r) {
        const float lq = __shfl(linv, 4*lkg + r, 64);
        const int t = tb + 4*lkg + r;
#pragma unroll
        for (int nf = 0; nf < 4; ++nf)
            AO[(size_t)(b*T_SEQ + t)*HID + h*HD + nf*16 + lr] = (bf16_t)(oacc[nf][r] * lq);
    }
}

extern "C" void kernel_launch(void* const* d_in, const int* in_sizes, int n_in,
                              void* d_out, int out_size, void* d_ws, size_t ws_size,
                              hipStream_t stream) {
    const float* x    = (const float*)d_in[0];
    const float* pos  = (const float*)d_in[1];
    const float* Wq   = (const float*)d_in[2];
    const float* Wk   = (const float*)d_in[3];
    const float* Wv   = (const float*)d_in[4];
    const float* Wo   = (const float*)d_in[5];
    const float* Wrel = (const float*)d_in[6];
    const float* bu   = (const float*)d_in[7];
    const float* bv   = (const float*)d_in[8];

    // workspace (bf16 elems): q 4M | k 4M | vT 4M | relk 2M | attn_out 4M = 36 MB
    bf16_t* ws  = (bf16_t*)d_ws;
    const size_t M1 = 1024u * 1024u;
    bf16_t* qb  = ws;
    bf16_t* kb  = ws + 4*M1;
    bf16_t* vtb = ws + 8*M1;
    bf16_t* rkb = ws + 12*M1;
    bf16_t* ab  = ws + 14*M1;

    // projections: y = x @ W^T  (M=4096 -> 256 blocks of 4 waves; M=2048 -> 128)
    gemm_xw<0,0><<<256, 256, 0, stream>>>(x,   Wq,   qb,  4096);
    gemm_xw<0,0><<<256, 256, 0, stream>>>(x,   Wk,   kb,  4096);
    gemm_xw<0,1><<<256, 256, 0, stream>>>(x,   Wv,   vtb, 4096);
    gemm_xw<0,0><<<128, 256, 0, stream>>>(pos, Wrel, rkb, 2048);

    attn_kernel<<<dim3(T_SEQ/64, NH, NB), 256, 0, stream>>>(qb, kb, vtb, rkb, bu, bv, ab);

    gemm_xw<1,2><<<256, 256, 0, stream>>>(ab, Wo, d_out, 4096);
}

// Round 4
// 662.461 us; speedup vs baseline: 1.2186x; 1.0057x over previous
//
#include <hip/hip_runtime.h>
#include <hip/hip_bf16.h>

#define T_SEQ 2048
#define HID   1024
#define NH    16
#define HD    64
#define NB    2

typedef __bf16 bf16_t;
typedef bf16_t bf16x8 __attribute__((ext_vector_type(8)));
typedef bf16_t bf16x4 __attribute__((ext_vector_type(4)));
typedef float  f32x4  __attribute__((ext_vector_type(4)));

static __device__ __forceinline__ f32x4 mfma16(bf16x8 a, bf16x8 b, f32x4 c) {
    return __builtin_amdgcn_mfma_f32_16x16x32_bf16(a, b, c, 0, 0, 0);
}

// One-time f32 -> bf16 conversion (same round-to-nearest as the old in-register path).
__global__ __launch_bounds__(256) void f32_to_bf16(const float* __restrict__ in,
                                                   bf16_t* __restrict__ out, int n8) {
    const int i = blockIdx.x * 256 + threadIdx.x;
    if (i < n8) {
        const float4* p = (const float4*)(in + (size_t)i * 8);
        float4 a0 = p[0], a1 = p[1];
        bf16x8 v;
        v[0]=(bf16_t)a0.x; v[1]=(bf16_t)a0.y; v[2]=(bf16_t)a0.z; v[3]=(bf16_t)a0.w;
        v[4]=(bf16_t)a1.x; v[5]=(bf16_t)a1.y; v[6]=(bf16_t)a1.z; v[7]=(bf16_t)a1.w;
        *(bf16x8*)(out + (size_t)i * 8) = v;
    }
}

// C[M x 1024] = A[M x 1024] @ W^T, W is [1024 x 1024] row-major (torch Linear).
// AMODE 0: A is f32 (convert in-register). AMODE 1: A is bf16.
// OMODE 0: bf16 out [M][1024]. OMODE 1: bf16 out transposed to [B][H][D][T] (for V).
// OMODE 2: f32 out [M][1024].
// cpx = gridDim.x/8 for XCD swizzle (consecutive logical blocks -> same XCD;
// a 32-block XCD chunk = 8 row-tiles x all 16 col-tiles: A 2MB + W 4MB in L2).
template<int AMODE, int OMODE>
__global__ __launch_bounds__(256) void gemm_xw(const void* __restrict__ Av,
                                               const float* __restrict__ W,
                                               void* __restrict__ outv, int M, int cpx) {
    const int hw = blockIdx.x;
    const int logical = (hw & 7) * cpx + (hw >> 3);
    const int wid  = logical * 4 + (threadIdx.x >> 6);
    const int lane = threadIdx.x & 63;
    const int mt = wid / 16, nt = wid % 16;
    const int row0 = mt * 64, col0 = nt * 64;
    const int lr = lane & 15;
    const int kd = (lane >> 4) * 8;

    f32x4 acc[4][4] = {};

    for (int k = 0; k < HID; k += 32) {
        bf16x8 af[4], bq[4];
#pragma unroll
        for (int i = 0; i < 4; ++i) {
            if (AMODE == 0) {
                const float* ap = (const float*)Av + (size_t)(row0 + i*16 + lr) * HID + k + kd;
                float4 a0 = *(const float4*)ap;
                float4 a1 = *(const float4*)(ap + 4);
                af[i][0]=(bf16_t)a0.x; af[i][1]=(bf16_t)a0.y; af[i][2]=(bf16_t)a0.z; af[i][3]=(bf16_t)a0.w;
                af[i][4]=(bf16_t)a1.x; af[i][5]=(bf16_t)a1.y; af[i][6]=(bf16_t)a1.z; af[i][7]=(bf16_t)a1.w;
            } else {
                af[i] = *(const bf16x8*)((const bf16_t*)Av + (size_t)(row0 + i*16 + lr) * HID + k + kd);
            }
        }
#pragma unroll
        for (int j = 0; j < 4; ++j) {
            const float* wp = W + (size_t)(col0 + j*16 + lr) * HID + k + kd;
            float4 b0 = *(const float4*)wp;
            float4 b1 = *(const float4*)(wp + 4);
            bq[j][0]=(bf16_t)b0.x; bq[j][1]=(bf16_t)b0.y; bq[j][2]=(bf16_t)b0.z; bq[j][3]=(bf16_t)b0.w;
            bq[j][4]=(bf16_t)b1.x; bq[j][5]=(bf16_t)b1.y; bq[j][6]=(bf16_t)b1.z; bq[j][7]=(bf16_t)b1.w;
        }
#pragma unroll
        for (int i = 0; i < 4; ++i)
#pragma unroll
            for (int j = 0; j < 4; ++j)
                acc[i][j] = mfma16(af[i], bq[j], acc[i][j]);
    }

    const int rb = (lane >> 4) * 4;
#pragma unroll
    for (int i = 0; i < 4; ++i) {
#pragma unroll
        for (int j = 0; j < 4; ++j) {
            const int col = col0 + j*16 + lr;
            if (OMODE == 0) {
                bf16_t* ob = (bf16_t*)outv;
#pragma unroll
                for (int r = 0; r < 4; ++r)
                    ob[(size_t)(row0 + i*16 + rb + r) * HID + col] = (bf16_t)acc[i][j][r];
            } else if (OMODE == 1) {
                const int row = row0 + i*16 + rb;      // 4 consecutive rows (= t)
                const int bb = row >> 11, t = row & (T_SEQ - 1);
                const int hh = col >> 6,  d = col & 63;
                bf16x4 pk;
#pragma unroll
                for (int r = 0; r < 4; ++r) pk[r] = (bf16_t)acc[i][j][r];
                *(bf16x4*)((bf16_t*)outv + ((size_t)((bb*NH + hh)*HD + d))*T_SEQ + t) = pk;
            } else {
                float* of = (float*)outv;
#pragma unroll
                for (int r = 0; r < 4; ++r)
                    of[(size_t)(row0 + i*16 + rb + r) * HID + col] = acc[i][j][r];
            }
        }
    }
}

// Fused rel-shift attention, SWAPPED orientation (see round 3 notes).
// Grid: 1024 blocks 1D with XCD swizzle; logical = tile + 32*h + 512*b so each
// XCD's 128-block chunk = 4 (b,h) pairs -> K/V/R working set ~3MB fits its L2.
// Lane layout D[s-row=4*(lane>>4)+reg][q-col=lane&15]: softmax row in-lane + 2 shfl.
// Exact rel_shift semantics (incl. unmasked upper-triangle leak):
//   s<=t   : (q[t]+bv)  . relk[T-1-(t-s)]
//   s==t+1 : 0
//   s>=t+2 : (q[t+1]+bv). relk[s-t-2]
// 0.125 softmax scale folded (exactly) into the bf16 q-fragments.
__global__ __launch_bounds__(256) void attn_kernel(
    const bf16_t* __restrict__ Q, const bf16_t* __restrict__ K,
    const bf16_t* __restrict__ VT, const bf16_t* __restrict__ RK,
    const float* __restrict__ bias_u, const float* __restrict__ bias_v,
    bf16_t* __restrict__ AO)
{
    const int hw = blockIdx.x;
    const int logical = (hw & 7) * 128 + (hw >> 3);
    const int tile = logical & 31;
    const int h    = (logical >> 5) & 15;
    const int b    = logical >> 9;

    const int w = threadIdx.x >> 6, lane = threadIdx.x & 63;
    const int t0 = tile * 64;
    const int lr = lane & 15, lkg = lane >> 4;
    const int kd = lkg * 8;

    __shared__ float  pp[4][16][84];     // [wave][q(=lr)][window col], f32x4 writes
    __shared__ bf16_t pl[4][16][72];     // [wave][q(=lr)][s offset], stride 72

    const int tb = t0 + w * 16;

    // Fragments (B-operand role): qu=(q[t]+bu)/8, qv=(q[t]+bv)/8,
    // qv2=(q[t+1]+bv)/8, t = tb+lr (clamped row for qv2).
    bf16x8 aqu[2], aqv[2], aqv2[2];
    {
        const int t  = tb + lr;
        const int t2 = (t + 1 < T_SEQ) ? t + 1 : T_SEQ - 1;
        const bf16_t* qp  = Q + ((size_t)(b*T_SEQ + t )*NH + h)*HD;
        const bf16_t* qp2 = Q + ((size_t)(b*T_SEQ + t2)*NH + h)*HD;
        const float* bu = bias_u + h*HD;
        const float* bv = bias_v + h*HD;
#pragma unroll
        for (int f = 0; f < 2; ++f) {
            const int k0 = f*32 + kd;
            bf16x8 q1 = *(const bf16x8*)(qp  + k0);
            bf16x8 q2 = *(const bf16x8*)(qp2 + k0);
#pragma unroll
            for (int j = 0; j < 8; ++j) {
                const float fu = bu[k0+j], fv = bv[k0+j];
                aqu [f][j] = (bf16_t)(((float)q1[j] + fu) * 0.125f);
                aqv [f][j] = (bf16_t)(((float)q1[j] + fv) * 0.125f);
                aqv2[f][j] = (bf16_t)(((float)q2[j] + fv) * 0.125f);
            }
        }
    }

    float m_run = -1e30f, l_run = 0.0f;   // per-lane stats for q = tb + lr
    f32x4 oacc[4];                        // [d-frag]: rows q=4lkg+r, col d=16nf+lr
    f32x4 zf = {0.f, 0.f, 0.f, 0.f};
#pragma unroll
    for (int nf = 0; nf < 4; ++nf) oacc[nf] = zf;

    const bf16_t* Kb = K  + (size_t)(b*T_SEQ)*HID + h*HD;
    const bf16_t* Vb = VT + (size_t)((b*NH + h)*HD)*T_SEQ;
    const bf16_t* Rb = RK + h*HD;
    const int d15 = 15 - lr;

    for (int s0 = 0; s0 < T_SEQ; s0 += 64) {
        // ---- content scores swapped: sc[j][r] = S[s=s0+16j+4lkg+r][q=tb+lr]
        f32x4 sc[4];
#pragma unroll
        for (int j = 0; j < 4; ++j) {
            const bf16_t* kp = Kb + (size_t)(s0 + j*16 + lr) * HID;
            bf16x8 a0 = *(const bf16x8*)(kp + kd);
            bf16x8 a1 = *(const bf16x8*)(kp + 32 + kd);
            __builtin_amdgcn_s_setprio(1);
            sc[j] = mfma16(a1, aqu[1], mfma16(a0, aqu[0], zf));
            __builtin_amdgcn_s_setprio(0);
        }

        // jwin = (s-s0) - lr + 15 = sof + d15, sof = 16j+4lkg+r in [0,63]
        // ---- branch 1 (s<=t): c1 = (s0-tb+T-16) + jwin
        if (s0 <= tb + 15) {
            const int base1 = s0 - tb + T_SEQ - 16;
#pragma unroll
            for (int jf = 0; jf < 5; ++jf) {
                const int c1 = base1 + jf*16 + lr;
                bf16x8 a0 = {}, a1 = {};
                if ((unsigned)c1 < (unsigned)T_SEQ) {
                    const bf16_t* rp = Rb + (size_t)c1 * HID;
                    a0 = *(const bf16x8*)(rp + kd);
                    a1 = *(const bf16x8*)(rp + 32 + kd);
                }
                __builtin_amdgcn_s_setprio(1);
                f32x4 c = mfma16(a1, aqv[1], mfma16(a0, aqv[0], zf));
                __builtin_amdgcn_s_setprio(0);
                *(f32x4*)&pp[w][lr][jf*16 + 4*lkg] = c;   // D[wcol=4lkg+r'][q=lr]
            }
#pragma unroll
            for (int j = 0; j < 4; ++j)
#pragma unroll
                for (int r = 0; r < 4; ++r) {
                    const int sof = 16*j + 4*lkg + r;
                    const int dt  = (s0 + sof) - (tb + lr);
                    const float v = pp[w][lr][sof + d15];
                    sc[j][r] += (dt <= 0) ? v : 0.0f;
                }
        }
        // ---- branch 2 (s>=t+2, query row t+1): c2 = (s0-tb-17) + jwin
        if (s0 >= tb - 61) {
            const int base2 = s0 - tb - 17;
#pragma unroll
            for (int jf = 0; jf < 5; ++jf) {
                const int c2 = base2 + jf*16 + lr;
                bf16x8 a0 = {}, a1 = {};
                if ((unsigned)c2 < (unsigned)T_SEQ) {
                    const bf16_t* rp = Rb + (size_t)c2 * HID;
                    a0 = *(const bf16x8*)(rp + kd);
                    a1 = *(const bf16x8*)(rp + 32 + kd);
                }
                __builtin_amdgcn_s_setprio(1);
                f32x4 c = mfma16(a1, aqv2[1], mfma16(a0, aqv2[0], zf));
                __builtin_amdgcn_s_setprio(0);
                *(f32x4*)&pp[w][lr][jf*16 + 4*lkg] = c;
            }
#pragma unroll
            for (int j = 0; j < 4; ++j)
#pragma unroll
                for (int r = 0; r < 4; ++r) {
                    const int sof = 16*j + 4*lkg + r;
                    const int dt  = (s0 + sof) - (tb + lr);
                    const float v = pp[w][lr][sof + d15];
                    sc[j][r] += (dt >= 2) ? v : 0.0f;
                }
        }

        // ---- online softmax: whole row is in-lane (16 vals) + 2 shfls
        float mx = fmaxf(fmaxf(fmaxf(sc[0][0], sc[0][1]), fmaxf(sc[0][2], sc[0][3])),
                         fmaxf(fmaxf(sc[1][0], sc[1][1]), fmaxf(sc[1][2], sc[1][3])));
        mx = fmaxf(mx, fmaxf(fmaxf(fmaxf(sc[2][0], sc[2][1]), fmaxf(sc[2][2], sc[2][3])),
                             fmaxf(fmaxf(sc[3][0], sc[3][1]), fmaxf(sc[3][2], sc[3][3]))));
        mx = fmaxf(mx, __shfl_xor(mx, 16, 64));
        mx = fmaxf(mx, __shfl_xor(mx, 32, 64));
        const float mnew = fmaxf(m_run, mx);
        const float fac = __expf(m_run - mnew);
        float sum = 0.0f;
#pragma unroll
        for (int j = 0; j < 4; ++j) {
            bf16x4 pk;
#pragma unroll
            for (int r = 0; r < 4; ++r) {
                const float p = __expf(sc[j][r] - mnew);
                sum += p;
                pk[r] = (bf16_t)p;
            }
            *(bf16x4*)&pl[w][lr][16*j + 4*lkg] = pk;     // P[q=lr][s=16j+4lkg+r]
        }
        sum += __shfl_xor(sum, 16, 64);
        sum += __shfl_xor(sum, 32, 64);
        l_run = l_run * fac + sum;
        m_run = mnew;

        // rescale O: rows are q=4lkg+r -> broadcast fac from lane (4lkg+r)
#pragma unroll
        for (int r = 0; r < 4; ++r) {
            const float facq = __shfl(fac, 4*lkg + r, 64);
#pragma unroll
            for (int nf = 0; nf < 4; ++nf) oacc[nf][r] *= facq;
        }

        // ---- PV: O += P @ V  (P A-frags from LDS; V^T rows contiguous)
        bf16x8 pa0 = *(const bf16x8*)(&pl[w][lr][kd]);
        bf16x8 pa1 = *(const bf16x8*)(&pl[w][lr][32 + kd]);
#pragma unroll
        for (int nf = 0; nf < 4; ++nf) {
            const bf16_t* vp = Vb + (size_t)(nf*16 + lr) * T_SEQ + s0;
            bf16x8 b0 = *(const bf16x8*)(vp + kd);
            bf16x8 b1 = *(const bf16x8*)(vp + 32 + kd);
            __builtin_amdgcn_s_setprio(1);
            oacc[nf] = mfma16(pa1, b1, mfma16(pa0, b0, oacc[nf]));
            __builtin_amdgcn_s_setprio(0);
        }
    }

    // ---- epilogue: normalize (broadcast 1/l to PV rows), store [B,T,H*D] bf16
    const float linv = 1.0f / l_run;
#pragma unroll
    for (int r = 0; r < 4; ++r) {
        const float lq = __shfl(linv, 4*lkg + r, 64);
        const int t = tb + 4*lkg + r;
#pragma unroll
        for (int nf = 0; nf < 4; ++nf)
            AO[(size_t)(b*T_SEQ + t)*HID + h*HD + nf*16 + lr] = (bf16_t)(oacc[nf][r] * lq);
    }
}

extern "C" void kernel_launch(void* const* d_in, const int* in_sizes, int n_in,
                              void* d_out, int out_size, void* d_ws, size_t ws_size,
                              hipStream_t stream) {
    const float* x    = (const float*)d_in[0];
    const float* pos  = (const float*)d_in[1];
    const float* Wq   = (const float*)d_in[2];
    const float* Wk   = (const float*)d_in[3];
    const float* Wv   = (const float*)d_in[4];
    const float* Wo   = (const float*)d_in[5];
    const float* Wrel = (const float*)d_in[6];
    const float* bu   = (const float*)d_in[7];
    const float* bv   = (const float*)d_in[8];

    // workspace (bf16 elems): q 4M | k 4M | vT 4M | relk 2M | ab 4M = 36 MB.
    // xb (bf16 copy of x) ALIASES ab: xb's last read (V proj) precedes ab's
    // first write (attn) in stream order.
    bf16_t* ws  = (bf16_t*)d_ws;
    const size_t M1 = 1024u * 1024u;
    bf16_t* qb  = ws;
    bf16_t* kb  = ws + 4*M1;
    bf16_t* vtb = ws + 8*M1;
    bf16_t* rkb = ws + 12*M1;
    bf16_t* ab  = ws + 14*M1;
    bf16_t* xb  = ab;

    f32_to_bf16<<<2048, 256, 0, stream>>>(x, xb, 524288);

    // projections: y = x @ W^T
    gemm_xw<1,0><<<256, 256, 0, stream>>>(xb,  Wq,   qb,  4096, 32);
    gemm_xw<1,0><<<256, 256, 0, stream>>>(xb,  Wk,   kb,  4096, 32);
    gemm_xw<1,1><<<256, 256, 0, stream>>>(xb,  Wv,   vtb, 4096, 32);
    gemm_xw<0,0><<<128, 256, 0, stream>>>(pos, Wrel, rkb, 2048, 16);

    attn_kernel<<<1024, 256, 0, stream>>>(qb, kb, vtb, rkb, bu, bv, ab);

    gemm_xw<1,2><<<256, 256, 0, stream>>>(ab, Wo, d_out, 4096, 32);
}

// Round 5
// 645.512 us; speedup vs baseline: 1.2506x; 1.0263x over previous
//
#include <hip/hip_runtime.h>
#include <hip/hip_bf16.h>

#define T_SEQ 2048
#define HID   1024
#define NH    16
#define HD    64
#define NB    2

typedef __bf16 bf16_t;
typedef bf16_t bf16x8 __attribute__((ext_vector_type(8)));
typedef bf16_t bf16x4 __attribute__((ext_vector_type(4)));
typedef float  f32x4  __attribute__((ext_vector_type(4)));

static __device__ __forceinline__ f32x4 mfma16(bf16x8 a, bf16x8 b, f32x4 c) {
    return __builtin_amdgcn_mfma_f32_16x16x32_bf16(a, b, c, 0, 0, 0);
}

// One-time f32 -> bf16 conversion (same round-to-nearest as in-register path).
__global__ __launch_bounds__(256) void f32_to_bf16(const float* __restrict__ in,
                                                   bf16_t* __restrict__ out, int n8) {
    const int i = blockIdx.x * 256 + threadIdx.x;
    if (i < n8) {
        const float4* p = (const float4*)(in + (size_t)i * 8);
        float4 a0 = p[0], a1 = p[1];
        bf16x8 v;
        v[0]=(bf16_t)a0.x; v[1]=(bf16_t)a0.y; v[2]=(bf16_t)a0.z; v[3]=(bf16_t)a0.w;
        v[4]=(bf16_t)a1.x; v[5]=(bf16_t)a1.y; v[6]=(bf16_t)a1.z; v[7]=(bf16_t)a1.w;
        *(bf16x8*)(out + (size_t)i * 8) = v;
    }
}

// C[M x 1024] = A[M x 1024] @ W^T, W row-major (torch Linear).
// AMODE 0: A f32 (convert in-register). AMODE 1: A bf16.
// OMODE 0: bf16 [M][1024]. OMODE 1: bf16 transposed to [B][H][D][T] (V). OMODE 2: f32.
template<int AMODE, int OMODE>
__global__ __launch_bounds__(256) void gemm_xw(const void* __restrict__ Av,
                                               const float* __restrict__ W,
                                               void* __restrict__ outv, int M, int cpx) {
    const int hw = blockIdx.x;
    const int logical = (hw & 7) * cpx + (hw >> 3);
    const int wid  = logical * 4 + (threadIdx.x >> 6);
    const int lane = threadIdx.x & 63;
    const int mt = wid / 16, nt = wid % 16;
    const int row0 = mt * 64, col0 = nt * 64;
    const int lr = lane & 15;
    const int kd = (lane >> 4) * 8;

    f32x4 acc[4][4] = {};

    for (int k = 0; k < HID; k += 32) {
        bf16x8 af[4], bq[4];
#pragma unroll
        for (int i = 0; i < 4; ++i) {
            if (AMODE == 0) {
                const float* ap = (const float*)Av + (size_t)(row0 + i*16 + lr) * HID + k + kd;
                float4 a0 = *(const float4*)ap;
                float4 a1 = *(const float4*)(ap + 4);
                af[i][0]=(bf16_t)a0.x; af[i][1]=(bf16_t)a0.y; af[i][2]=(bf16_t)a0.z; af[i][3]=(bf16_t)a0.w;
                af[i][4]=(bf16_t)a1.x; af[i][5]=(bf16_t)a1.y; af[i][6]=(bf16_t)a1.z; af[i][7]=(bf16_t)a1.w;
            } else {
                af[i] = *(const bf16x8*)((const bf16_t*)Av + (size_t)(row0 + i*16 + lr) * HID + k + kd);
            }
        }
#pragma unroll
        for (int j = 0; j < 4; ++j) {
            const float* wp = W + (size_t)(col0 + j*16 + lr) * HID + k + kd;
            float4 b0 = *(const float4*)wp;
            float4 b1 = *(const float4*)(wp + 4);
            bq[j][0]=(bf16_t)b0.x; bq[j][1]=(bf16_t)b0.y; bq[j][2]=(bf16_t)b0.z; bq[j][3]=(bf16_t)b0.w;
            bq[j][4]=(bf16_t)b1.x; bq[j][5]=(bf16_t)b1.y; bq[j][6]=(bf16_t)b1.z; bq[j][7]=(bf16_t)b1.w;
        }
#pragma unroll
        for (int i = 0; i < 4; ++i)
#pragma unroll
            for (int j = 0; j < 4; ++j)
                acc[i][j] = mfma16(af[i], bq[j], acc[i][j]);
    }

    const int rb = (lane >> 4) * 4;
#pragma unroll
    for (int i = 0; i < 4; ++i) {
#pragma unroll
        for (int j = 0; j < 4; ++j) {
            const int col = col0 + j*16 + lr;
            if (OMODE == 0) {
                bf16_t* ob = (bf16_t*)outv;
#pragma unroll
                for (int r = 0; r < 4; ++r)
                    ob[(size_t)(row0 + i*16 + rb + r) * HID + col] = (bf16_t)acc[i][j][r];
            } else if (OMODE == 1) {
                const int row = row0 + i*16 + rb;
                const int bb = row >> 11, t = row & (T_SEQ - 1);
                const int hh = col >> 6,  d = col & 63;
                bf16x4 pk;
#pragma unroll
                for (int r = 0; r < 4; ++r) pk[r] = (bf16_t)acc[i][j][r];
                *(bf16x4*)((bf16_t*)outv + ((size_t)((bb*NH + hh)*HD + d))*T_SEQ + t) = pk;
            } else {
                float* of = (float*)outv;
#pragma unroll
                for (int r = 0; r < 4; ++r)
                    of[(size_t)(row0 + i*16 + rb + r) * HID + col] = acc[i][j][r];
            }
        }
    }
}

// Fused rel-shift attention, SWAPPED orientation, optional KV-split.
// NSPLIT=1: grid 1024, full s-range, normalize + store AO.
// NSPLIT=2: grid 2048, each block does half the s-range (16 tiles), stores
//           unnormalized O (f32) + m,l partials for the combine kernel.
// XCD swizzle: consecutive logical blocks -> same XCD; chunk covers 4 (b,h)
// working sets (~3MB K/V/R) per XCD L2.
// Lane layout D[s-row=4*(lane>>4)+reg][q-col=lane&15]: softmax row in-lane + 2 shfl.
// Exact rel_shift semantics (incl. unmasked upper-triangle leak):
//   s<=t: (q[t]+bv).relk[T-1-(t-s)] | s==t+1: 0 | s>=t+2: (q[t+1]+bv).relk[s-t-2]
// 0.125 scale folded (exactly) into the bf16 q-fragments.
template<int NSPLIT>
__global__ __launch_bounds__(256) void attn_kernel(
    const bf16_t* __restrict__ Q, const bf16_t* __restrict__ K,
    const bf16_t* __restrict__ VT, const bf16_t* __restrict__ RK,
    const float* __restrict__ bias_u, const float* __restrict__ bias_v,
    bf16_t* __restrict__ AO, float* __restrict__ PO, float* __restrict__ ML,
    int cpx)
{
    const int hw = blockIdx.x;
    const int logical = (hw & 7) * cpx + (hw >> 3);
    const int tile = logical & 31;
    int h, b, split;
    if (NSPLIT == 1) {
        split = 0; h = (logical >> 5) & 15; b = logical >> 9;
    } else {
        split = (logical >> 5) & 1; h = (logical >> 6) & 15; b = logical >> 10;
    }

    const int w = threadIdx.x >> 6, lane = threadIdx.x & 63;
    const int t0 = tile * 64;
    const int lr = lane & 15, lkg = lane >> 4;
    const int kd = lkg * 8;

    __shared__ float  pp[4][16][84];     // [wave][q(=lr)][window col]
    __shared__ bf16_t pl[4][16][72];     // [wave][q(=lr)][s offset]

    const int tb = t0 + w * 16;

    bf16x8 aqu[2], aqv[2], aqv2[2];
    {
        const int t  = tb + lr;
        const int t2 = (t + 1 < T_SEQ) ? t + 1 : T_SEQ - 1;
        const bf16_t* qp  = Q + ((size_t)(b*T_SEQ + t )*NH + h)*HD;
        const bf16_t* qp2 = Q + ((size_t)(b*T_SEQ + t2)*NH + h)*HD;
        const float* bu = bias_u + h*HD;
        const float* bv = bias_v + h*HD;
#pragma unroll
        for (int f = 0; f < 2; ++f) {
            const int k0 = f*32 + kd;
            bf16x8 q1 = *(const bf16x8*)(qp  + k0);
            bf16x8 q2 = *(const bf16x8*)(qp2 + k0);
#pragma unroll
            for (int j = 0; j < 8; ++j) {
                const float fu = bu[k0+j], fv = bv[k0+j];
                aqu [f][j] = (bf16_t)(((float)q1[j] + fu) * 0.125f);
                aqv [f][j] = (bf16_t)(((float)q1[j] + fv) * 0.125f);
                aqv2[f][j] = (bf16_t)(((float)q2[j] + fv) * 0.125f);
            }
        }
    }

    float m_run = -1e30f, l_run = 0.0f;   // per-lane stats for q = tb + lr
    f32x4 oacc[4];                        // rows q=4lkg+r, col d=16nf+lr
    f32x4 zf = {0.f, 0.f, 0.f, 0.f};
#pragma unroll
    for (int nf = 0; nf < 4; ++nf) oacc[nf] = zf;

    const bf16_t* Kb = K  + (size_t)(b*T_SEQ)*HID + h*HD;
    const bf16_t* Vb = VT + (size_t)((b*NH + h)*HD)*T_SEQ;
    const bf16_t* Rb = RK + h*HD;
    const int d15 = 15 - lr;
    const int sBeg = split * (T_SEQ / NSPLIT);

    for (int ss = 0; ss < T_SEQ / NSPLIT; ss += 64) {
        const int s0 = sBeg + ss;
        // ---- content scores: sc[j][r] = S[s=s0+16j+4lkg+r][q=tb+lr]
        f32x4 sc[4];
#pragma unroll
        for (int j = 0; j < 4; ++j) {
            const bf16_t* kp = Kb + (size_t)(s0 + j*16 + lr) * HID;
            bf16x8 a0 = *(const bf16x8*)(kp + kd);
            bf16x8 a1 = *(const bf16x8*)(kp + 32 + kd);
            sc[j] = mfma16(a1, aqu[1], mfma16(a0, aqu[0], zf));
        }

        // jwin = sof + d15, sof = 16j+4lkg+r in [0,63]
        // ---- branch 1 (s<=t): c1 = (s0-tb+T-16) + jwin
        if (s0 <= tb + 15) {
            const int base1 = s0 - tb + T_SEQ - 16;
#pragma unroll
            for (int jf = 0; jf < 5; ++jf) {
                const int c1 = base1 + jf*16 + lr;
                bf16x8 a0 = {}, a1 = {};
                if ((unsigned)c1 < (unsigned)T_SEQ) {
                    const bf16_t* rp = Rb + (size_t)c1 * HID;
                    a0 = *(const bf16x8*)(rp + kd);
                    a1 = *(const bf16x8*)(rp + 32 + kd);
                }
                f32x4 c = mfma16(a1, aqv[1], mfma16(a0, aqv[0], zf));
                *(f32x4*)&pp[w][lr][jf*16 + 4*lkg] = c;
            }
#pragma unroll
            for (int j = 0; j < 4; ++j)
#pragma unroll
                for (int r = 0; r < 4; ++r) {
                    const int sof = 16*j + 4*lkg + r;
                    const int dt  = (s0 + sof) - (tb + lr);
                    const float v = pp[w][lr][sof + d15];
                    sc[j][r] += (dt <= 0) ? v : 0.0f;
                }
        }
        // ---- branch 2 (s>=t+2, query row t+1): c2 = (s0-tb-17) + jwin
        if (s0 >= tb - 61) {
            const int base2 = s0 - tb - 17;
#pragma unroll
            for (int jf = 0; jf < 5; ++jf) {
                const int c2 = base2 + jf*16 + lr;
                bf16x8 a0 = {}, a1 = {};
                if ((unsigned)c2 < (unsigned)T_SEQ) {
                    const bf16_t* rp = Rb + (size_t)c2 * HID;
                    a0 = *(const bf16x8*)(rp + kd);
                    a1 = *(const bf16x8*)(rp + 32 + kd);
                }
                f32x4 c = mfma16(a1, aqv2[1], mfma16(a0, aqv2[0], zf));
                *(f32x4*)&pp[w][lr][jf*16 + 4*lkg] = c;
            }
#pragma unroll
            for (int j = 0; j < 4; ++j)
#pragma unroll
                for (int r = 0; r < 4; ++r) {
                    const int sof = 16*j + 4*lkg + r;
                    const int dt  = (s0 + sof) - (tb + lr);
                    const float v = pp[w][lr][sof + d15];
                    sc[j][r] += (dt >= 2) ? v : 0.0f;
                }
        }

        // ---- online softmax: row in-lane (16 vals) + 2 shfls
        float mx = fmaxf(fmaxf(fmaxf(sc[0][0], sc[0][1]), fmaxf(sc[0][2], sc[0][3])),
                         fmaxf(fmaxf(sc[1][0], sc[1][1]), fmaxf(sc[1][2], sc[1][3])));
        mx = fmaxf(mx, fmaxf(fmaxf(fmaxf(sc[2][0], sc[2][1]), fmaxf(sc[2][2], sc[2][3])),
                             fmaxf(fmaxf(sc[3][0], sc[3][1]), fmaxf(sc[3][2], sc[3][3]))));
        mx = fmaxf(mx, __shfl_xor(mx, 16, 64));
        mx = fmaxf(mx, __shfl_xor(mx, 32, 64));
        const float mnew = fmaxf(m_run, mx);
        const float fac = __expf(m_run - mnew);
        float sum = 0.0f;
#pragma unroll
        for (int j = 0; j < 4; ++j) {
            bf16x4 pk;
#pragma unroll
            for (int r = 0; r < 4; ++r) {
                const float p = __expf(sc[j][r] - mnew);
                sum += p;
                pk[r] = (bf16_t)p;
            }
            *(bf16x4*)&pl[w][lr][16*j + 4*lkg] = pk;
        }
        sum += __shfl_xor(sum, 16, 64);
        sum += __shfl_xor(sum, 32, 64);
        l_run = l_run * fac + sum;
        m_run = mnew;

#pragma unroll
        for (int r = 0; r < 4; ++r) {
            const float facq = __shfl(fac, 4*lkg + r, 64);
#pragma unroll
            for (int nf = 0; nf < 4; ++nf) oacc[nf][r] *= facq;
        }

        // ---- PV: O += P @ V
        bf16x8 pa0 = *(const bf16x8*)(&pl[w][lr][kd]);
        bf16x8 pa1 = *(const bf16x8*)(&pl[w][lr][32 + kd]);
#pragma unroll
        for (int nf = 0; nf < 4; ++nf) {
            const bf16_t* vp = Vb + (size_t)(nf*16 + lr) * T_SEQ + s0;
            bf16x8 b0 = *(const bf16x8*)(vp + kd);
            bf16x8 b1 = *(const bf16x8*)(vp + 32 + kd);
            oacc[nf] = mfma16(pa1, b1, mfma16(pa0, b0, oacc[nf]));
        }
    }

    if (NSPLIT == 1) {
        const float linv = 1.0f / l_run;
#pragma unroll
        for (int r = 0; r < 4; ++r) {
            const float lq = __shfl(linv, 4*lkg + r, 64);
            const int t = tb + 4*lkg + r;
#pragma unroll
            for (int nf = 0; nf < 4; ++nf)
                AO[(size_t)(b*T_SEQ + t)*HID + h*HD + nf*16 + lr] = (bf16_t)(oacc[nf][r] * lq);
        }
    } else {
        // partial store: unnormalized O (f32) + m,l
        float* po = PO + (((size_t)split*NB*NH + b*NH + h)*T_SEQ)*HD;
#pragma unroll
        for (int r = 0; r < 4; ++r)
#pragma unroll
            for (int nf = 0; nf < 4; ++nf)
                po[(size_t)(tb + 4*lkg + r)*HD + nf*16 + lr] = oacc[nf][r];
        if (lkg == 0) {
            float* ml = ML + ((size_t)split*NB*NH + b*NH + h)*2*T_SEQ;
            ml[tb + lr] = m_run;
            ml[T_SEQ + tb + lr] = l_run;
        }
    }
}

// Flash combine of the 2 KV-split partials -> AO bf16 [B,T,H*D].
__global__ __launch_bounds__(256) void combine_kernel(
    const float* __restrict__ PO, const float* __restrict__ ML,
    bf16_t* __restrict__ AO)
{
    const int idx = blockIdx.x * 256 + threadIdx.x;    // 65536 = B*H*T
    const int t = idx & (T_SEQ - 1);
    const int h = (idx >> 11) & (NH - 1);
    const int b = idx >> 15;
    const size_t poS = (size_t)NB*NH*T_SEQ*HD;
    const size_t mlS = (size_t)NB*NH*2*T_SEQ;
    const float* po1 = PO + (((size_t)b*NH + h)*T_SEQ + t)*HD;
    const float* po2 = po1 + poS;
    const float* ml1 = ML + ((size_t)b*NH + h)*2*T_SEQ;
    const float* ml2 = ml1 + mlS;
    const float m1 = ml1[t], l1 = ml1[T_SEQ + t];
    const float m2 = ml2[t], l2 = ml2[T_SEQ + t];
    const float M  = fmaxf(m1, m2);
    float f1 = __expf(m1 - M), f2 = __expf(m2 - M);
    const float linv = 1.0f / (f1*l1 + f2*l2);
    f1 *= linv; f2 *= linv;
    bf16_t* ao = AO + ((size_t)b*T_SEQ + t)*HID + h*HD;
#pragma unroll
    for (int d = 0; d < HD; d += 8) {
        f32x4 a0 = *(const f32x4*)(po1 + d), a1 = *(const f32x4*)(po1 + d + 4);
        f32x4 c0 = *(const f32x4*)(po2 + d), c1 = *(const f32x4*)(po2 + d + 4);
        bf16x8 o;
#pragma unroll
        for (int j = 0; j < 4; ++j) {
            o[j]     = (bf16_t)(f1*a0[j] + f2*c0[j]);
            o[4 + j] = (bf16_t)(f1*a1[j] + f2*c1[j]);
        }
        *(bf16x8*)(ao + d) = o;
    }
}

extern "C" void kernel_launch(void* const* d_in, const int* in_sizes, int n_in,
                              void* d_out, int out_size, void* d_ws, size_t ws_size,
                              hipStream_t stream) {
    const float* x    = (const float*)d_in[0];
    const float* pos  = (const float*)d_in[1];
    const float* Wq   = (const float*)d_in[2];
    const float* Wk   = (const float*)d_in[3];
    const float* Wv   = (const float*)d_in[4];
    const float* Wo   = (const float*)d_in[5];
    const float* Wrel = (const float*)d_in[6];
    const float* bu   = (const float*)d_in[7];
    const float* bv   = (const float*)d_in[8];

    // ws layout (bf16 elems): q 4M | k 4M | vT 4M | relk 2M | ab 4M  = 36 MiB,
    // then (if room) PO f32 partials 64 MiB + ML 1 MiB for KV-split.
    // xb (bf16 x) aliases ab: last read (V proj) precedes ab's first write.
    bf16_t* ws  = (bf16_t*)d_ws;
    const size_t M1 = 1024u * 1024u;
    bf16_t* qb  = ws;
    bf16_t* kb  = ws + 4*M1;
    bf16_t* vtb = ws + 8*M1;
    bf16_t* rkb = ws + 12*M1;
    bf16_t* ab  = ws + 14*M1;
    bf16_t* xb  = ab;

    const size_t baseBytes = 18*M1*2;
    const size_t poBytes = (size_t)2*NB*NH*T_SEQ*HD*4;
    const size_t mlBytes = (size_t)2*NB*NH*2*T_SEQ*4;
    float* PO = (float*)((char*)d_ws + baseBytes);
    float* ML = (float*)((char*)d_ws + baseBytes + poBytes);
    const bool split2 = ws_size >= baseBytes + poBytes + mlBytes;

    f32_to_bf16<<<2048, 256, 0, stream>>>(x, xb, 524288);

    gemm_xw<1,0><<<256, 256, 0, stream>>>(xb,  Wq,   qb,  4096, 32);
    gemm_xw<1,0><<<256, 256, 0, stream>>>(xb,  Wk,   kb,  4096, 32);
    gemm_xw<1,1><<<256, 256, 0, stream>>>(xb,  Wv,   vtb, 4096, 32);
    gemm_xw<0,0><<<128, 256, 0, stream>>>(pos, Wrel, rkb, 2048, 16);

    if (split2) {
        attn_kernel<2><<<2048, 256, 0, stream>>>(qb, kb, vtb, rkb, bu, bv, ab, PO, ML, 256);
        combine_kernel<<<256, 256, 0, stream>>>(PO, ML, ab);
    } else {
        attn_kernel<1><<<1024, 256, 0, stream>>>(qb, kb, vtb, rkb, bu, bv, ab, nullptr, nullptr, 128);
    }

    gemm_xw<1,2><<<256, 256, 0, stream>>>(ab, Wo, d_out, 4096, 32);
}